// Round 12
// baseline (47.473 us; speedup 1.0000x reference)
//
#include <hip/hip_runtime.h>
#include <math.h>

#define B_TOTAL 2048
#define I_DIM   128
#define O_DIM   128
#define GK      68
#define NKNOT   71
#define KP      72                   // padded K per i (mult of 8)
#define NKS     288                  // total k-steps of 32 (128*72/32)
#define IRANGES 32                   // K-split: 4 i / 9 ksteps per block
#define KS_BLK  9
#define PART_PER ((size_t)B_TOTAL * O_DIM)           // 262144
#define PART_F   ((size_t)IRANGES * PART_PER)        // 8.39M floats
#define CDF_OFF  (PART_F * 4)                        // 33.55 MB
#define CDF_ELEMS ((size_t)128 * NKS * 512)          // 18.87M bf16
#define BF_OFF   (CDF_OFF + CDF_ELEMS * 2)
#define BF_ELEMS ((size_t)NKS * 8 * 512)             // 1.18M bf16
#define WS_NEED  (BF_OFF + BF_ELEMS * 2)             // ~73.7 MB

typedef short s16x8 __attribute__((ext_vector_type(8)));
typedef float f32x4 __attribute__((ext_vector_type(4)));

__device__ __forceinline__ unsigned short f2bf(float f) {   // RNE
    unsigned u = __float_as_uint(f);
    return (unsigned short)((u + 0x7fffu + ((u >> 16) & 1u)) >> 16);
}
__device__ __forceinline__ float rdlanef(float v, int sl) {
    return __int_as_float(__builtin_amdgcn_readlane(__float_as_int(v), sl));
}

__device__ __forceinline__ void coef_eval(float xv, const float* t_sh,
                                          float& c0, float& c1, float& c2,
                                          float& c3, float& c4, int& g0) {
    int ik = 3 + (int)floorf((xv + 1.0f) * 32.0f);
    ik = min(max(ik, 3), 66);
    while (ik < 66 && xv >= t_sh[ik + 1]) ++ik;
    while (ik > 3 && xv < t_sh[ik]) --ik;
    float l0, l1, l2, r0, r1, r2;
    float N0 = 1.0f, N1, N2, N3;
    l0 = xv - t_sh[ik];  r0 = t_sh[ik + 1] - xv;
    { float temp = N0 / (r0 + l0); N0 = r0 * temp; N1 = l0 * temp; }
    l1 = xv - t_sh[ik - 1];  r1 = t_sh[ik + 2] - xv;
    { float saved = 0.0f, temp;
      temp = N0 / (r0 + l1); N0 = saved + r0 * temp; saved = l1 * temp;
      temp = N1 / (r1 + l0); N1 = saved + r1 * temp; N2 = l0 * temp; }
    l2 = xv - t_sh[ik - 2];  r2 = t_sh[ik + 3] - xv;
    { float saved = 0.0f, temp;
      temp = N0 / (r0 + l2); N0 = saved + r0 * temp; saved = l2 * temp;
      temp = N1 / (r1 + l1); N1 = saved + r1 * temp; saved = l1 * temp;
      temp = N2 / (r2 + l0); N2 = saved + r2 * temp; N3 = l0 * temp; }
    c0 = N0; c1 = N1; c2 = N2; c3 = N3;
    c4 = xv / (1.0f + expf(-xv));
    g0 = ik - 3;
}

// A-fragment build: Cdf[bt16][kstep][lane][8], elem j = Cd[b=bt16*16+(l&15)]
// [k=kstep*32+(l>>4)*8+j] with k -> (i=k/72, kk=k%72):
// val = N_{kk-g0} | silu(kk==67) | 0. One coef eval per lane; coalesced 16B store.
// grid = 128*288/4 = 9216 blocks x 256 thr (4 waves, wave = one kstep).
__global__ __launch_bounds__(256)
void build_a(const float* __restrict__ x, const float* __restrict__ t,
             unsigned short* __restrict__ cdf) {
    __shared__ float t_sh[NKNOT];
    const int tid = threadIdx.x;
    if (tid < NKNOT) t_sh[tid] = t[tid];
    __syncthreads();

    const int bt16  = blockIdx.x / (NKS / 4);
    const int grp   = blockIdx.x % (NKS / 4);
    const int wave  = tid >> 6;
    const int l     = tid & 63;
    const int kstep = grp * 4 + wave;
    const int k0    = kstep * 32 + ((l >> 4) << 3);
    const int i     = k0 / KP;
    const int kk0   = k0 - i * KP;
    const int b     = bt16 * 16 + (l & 15);

    float c0, c1, c2, c3, c4; int g0;
    coef_eval(x[(size_t)b * I_DIM + i], t_sh, c0, c1, c2, c3, c4, g0);

    unsigned short v[8];
    #pragma unroll
    for (int j = 0; j < 8; ++j) {
        const int kk = kk0 + j;
        const int dk = kk - g0;
        float f = 0.0f;
        f = (dk == 0) ? c0 : f;
        f = (dk == 1) ? c1 : f;
        f = (dk == 2) ? c2 : f;
        f = (dk == 3) ? c3 : f;
        f = (kk == 67) ? c4 : f;
        v[j] = f2bf(f);
    }
    uint4 st;
    st.x = (unsigned)v[0] | ((unsigned)v[1] << 16);
    st.y = (unsigned)v[2] | ((unsigned)v[3] << 16);
    st.z = (unsigned)v[4] | ((unsigned)v[5] << 16);
    st.w = (unsigned)v[6] | ((unsigned)v[7] << 16);
    *(uint4*)(cdf + (((size_t)bt16 * NKS + kstep) << 9) + l * 8) = st;
}

// B-fragment build: Bf[kstep][ntile][lane][8], elem j =
// W[kk][i][n=ntile*16+(l&15)] (kk=k%72<68 else 0), k=kstep*32+(l>>4)*8+j.
// grid = 288*8/4 = 576 blocks x 256 thr.
__global__ __launch_bounds__(256)
void build_b(const float* __restrict__ w, unsigned short* __restrict__ bfr) {
    const int tid   = threadIdx.x;
    const int kstep = blockIdx.x >> 1;
    const int wave  = tid >> 6;
    const int l     = tid & 63;
    const int ntile = (blockIdx.x & 1) * 4 + wave;
    const int n     = ntile * 16 + (l & 15);
    const int k0    = kstep * 32 + ((l >> 4) << 3);
    const int i     = k0 / KP;
    const int kk0   = k0 - i * KP;

    unsigned short v[8];
    #pragma unroll
    for (int j = 0; j < 8; ++j) {
        const int kk = kk0 + j;
        float f = 0.0f;
        if (kk < GK) f = w[(size_t)kk * (I_DIM * O_DIM) + (size_t)i * O_DIM + n];
        v[j] = f2bf(f);
    }
    uint4 st;
    st.x = (unsigned)v[0] | ((unsigned)v[1] << 16);
    st.y = (unsigned)v[2] | ((unsigned)v[3] << 16);
    st.z = (unsigned)v[4] | ((unsigned)v[5] << 16);
    st.w = (unsigned)v[6] | ((unsigned)v[7] << 16);
    *(uint4*)(bfr + (((size_t)kstep * 8 + ntile) << 9) + l * 8) = st;
}

// GEMM: grid = 16 bt128 x 32 iranges = 512 blocks (2/CU), 512 thr (8 waves).
// BM=128, BN=128, 9 ksteps of K=32. Wave (wm=wave>>1, wn=wave&1) owns
// 2 mtiles x 4 ntiles. Per kstep: stage next (16 x 1KB global_load_lds),
// 2 A + 4 B ds_read_b128 (conflict-free), 8 MFMA 16x16x32_bf16.
__global__ __launch_bounds__(512, 4)
void gemm(const unsigned short* __restrict__ cdf,
          const unsigned short* __restrict__ bfr,
          float* __restrict__ part) {
    __shared__ __align__(16) unsigned short sA[2][8 * 512];
    __shared__ __align__(16) unsigned short sB[2][8 * 512];

    const int tid   = threadIdx.x;
    const int bt128 = blockIdx.x >> 5;
    const int ir    = blockIdx.x & 31;
    const int ksb   = ir * KS_BLK;
    const int wave  = tid >> 6;
    const int l     = tid & 63;
    const int wm    = wave >> 1;
    const int wn    = wave & 1;

    auto stage = [&](int sel, int ks) {
        const unsigned short* srcA =
            cdf + (((size_t)(bt128 * 8 + wave) * NKS + ks) << 9) + l * 8;
        const unsigned short* srcB =
            bfr + (((size_t)ks * 8 + wave) << 9) + l * 8;
        __builtin_amdgcn_global_load_lds(
            (const __attribute__((address_space(1))) void*)srcA,
            (__attribute__((address_space(3))) void*)&sA[sel][wave * 512], 16, 0, 0);
        __builtin_amdgcn_global_load_lds(
            (const __attribute__((address_space(1))) void*)srcB,
            (__attribute__((address_space(3))) void*)&sB[sel][wave * 512], 16, 0, 0);
    };

    f32x4 acc[2][4];
    #pragma unroll
    for (int mi = 0; mi < 2; ++mi)
        #pragma unroll
        for (int ni = 0; ni < 4; ++ni) acc[mi][ni] = (f32x4)0.0f;

    stage(0, ksb);
    __syncthreads();

    for (int s = 0; s < KS_BLK; ++s) {
        const int sel = s & 1;
        if (s + 1 < KS_BLK) stage(sel ^ 1, ksb + s + 1);

        const s16x8 a0 = *(const s16x8*)&sA[sel][(wm * 2 + 0) * 512 + l * 8];
        const s16x8 a1 = *(const s16x8*)&sA[sel][(wm * 2 + 1) * 512 + l * 8];
        #pragma unroll
        for (int ni = 0; ni < 4; ++ni) {
            const s16x8 bb = *(const s16x8*)&sB[sel][(wn * 4 + ni) * 512 + l * 8];
            acc[0][ni] = __builtin_amdgcn_mfma_f32_16x16x32_bf16(a0, bb, acc[0][ni], 0, 0, 0);
            acc[1][ni] = __builtin_amdgcn_mfma_f32_16x16x32_bf16(a1, bb, acc[1][ni], 0, 0, 0);
        }
        __syncthreads();
    }

    // D: row = (l>>4)*4 + r (m), col = l&15 (n)  [m89-verified, R10-proven]
    float* pb = part + (size_t)ir * PART_PER;
    #pragma unroll
    for (int mi = 0; mi < 2; ++mi) {
        #pragma unroll
        for (int ni = 0; ni < 4; ++ni) {
            const int o = (wn * 4 + ni) * 16 + (l & 15);
            #pragma unroll
            for (int r = 0; r < 4; ++r) {
                const int b = bt128 * 128 + (wm * 2 + mi) * 16 + (l >> 4) * 4 + r;
                pb[(size_t)b * O_DIM + o] = acc[mi][ni][r];
            }
        }
    }
}

// out[b][o] = sum over 32 iranges
__global__ __launch_bounds__(256)
void reduce32(const float* __restrict__ part, float* __restrict__ out) {
    const int f = blockIdx.x * 256 + threadIdx.x;       // < 65536
    const float4* base = (const float4*)part + f;
    float4 s = make_float4(0.0f, 0.0f, 0.0f, 0.0f);
    #pragma unroll
    for (int r2 = 0; r2 < IRANGES; ++r2) {
        const float4 v = base[(size_t)r2 * (PART_PER / 4)];
        s.x += v.x; s.y += v.y; s.z += v.z; s.w += v.w;
    }
    ((float4*)out)[f] = s;
}

// Fallback: R9-style direct f32 gather (works with any ws).
__global__ __launch_bounds__(256)
void flashkan_gather_f32(const float* __restrict__ x,
                         const float* __restrict__ w,
                         const float* __restrict__ t,
                         float* __restrict__ out) {
    __shared__ float t_sh[NKNOT];
    __shared__ float psum[4][O_DIM];
    const int tid  = threadIdx.x;
    const int b    = blockIdx.x;
    const int wave = tid >> 6;
    const int lane = tid & 63;
    const int l32  = lane & 31;
    if (tid < NKNOT) t_sh[tid] = t[tid];
    __syncthreads();
    float cf0, cf1, cf2, cf3, cf4; int cg;
    coef_eval(x[(size_t)b * I_DIM + wave * 32 + l32], t_sh,
              cf0, cf1, cf2, cf3, cf4, cg);
    const int i_base = wave * 32;
    float ax = 0.0f, ay = 0.0f;
    #pragma unroll 8
    for (int k = 0; k < 32; ++k) {
        const float c0 = rdlanef(cf0, k), c1 = rdlanef(cf1, k);
        const float c2 = rdlanef(cf2, k), c3 = rdlanef(cf3, k);
        const float c4 = rdlanef(cf4, k);
        const int   g0 = __builtin_amdgcn_readlane(cg, k);
        const int i = i_base + k;
        const float2* base = (const float2*)(w + (size_t)i * O_DIM) + lane;
        const size_t rs = (size_t)I_DIM * O_DIM / 2;
        const float2 v0 = base[(size_t)g0 * rs];
        const float2 v1 = base[(size_t)(g0 + 1) * rs];
        const float2 v2 = base[(size_t)(g0 + 2) * rs];
        const float2 v3 = base[(size_t)(g0 + 3) * rs];
        const float2 v4 = base[(size_t)(GK - 1) * rs];
        ax += c0 * v0.x + c1 * v1.x + c2 * v2.x + c3 * v3.x + c4 * v4.x;
        ay += c0 * v0.y + c1 * v1.y + c2 * v2.y + c3 * v3.y + c4 * v4.y;
    }
    psum[wave][lane * 2]     = ax;
    psum[wave][lane * 2 + 1] = ay;
    __syncthreads();
    if (tid < O_DIM) {
        out[(size_t)b * O_DIM + tid] =
            psum[0][tid] + psum[1][tid] + psum[2][tid] + psum[3][tid];
    }
}

extern "C" void kernel_launch(void* const* d_in, const int* in_sizes, int n_in,
                              void* d_out, int out_size, void* d_ws, size_t ws_size,
                              hipStream_t stream) {
    const float* x = (const float*)d_in[0];
    const float* w = (const float*)d_in[1];
    const float* t = (const float*)d_in[2];
    float* out = (float*)d_out;

    if (ws_size >= WS_NEED) {
        float* part = (float*)d_ws;
        unsigned short* cdf = (unsigned short*)((char*)d_ws + CDF_OFF);
        unsigned short* bfr = (unsigned short*)((char*)d_ws + BF_OFF);
        build_b<<<NKS * 8 / 4, 256, 0, stream>>>(w, bfr);
        build_a<<<128 * NKS / 4, 256, 0, stream>>>(x, t, cdf);
        gemm<<<16 * IRANGES, 512, 0, stream>>>(cdf, bfr, part);
        reduce32<<<(int)(PART_PER / 4 / 256), 256, 0, stream>>>(part, out);
    } else {
        flashkan_gather_f32<<<B_TOTAL, 256, 0, stream>>>(x, w, t, out);
    }
}

// Round 13
// 32.193 us; speedup vs baseline: 1.4747x; 1.4747x over previous
//
#include <hip/hip_runtime.h>
#include <math.h>

#define B_TOTAL 2048
#define I_DIM   128
#define O_DIM   128
#define GK      68                  // G + k rows
#define NKNOT   71
#define W_ELEMS ((size_t)GK * I_DIM * O_DIM)    // 1114112
#define WS_MIN  (W_ELEMS * 2)                   // 2.23 MB bf16 copy
#define SLICE_DW (GK * O_DIM / 2)               // 4352 dwords per i-slice
#define ROW_DW   (O_DIM / 2)                    // 64 dwords per row

__device__ __forceinline__ float rdlanef(float v, int sl) {
    return __int_as_float(__builtin_amdgcn_readlane(__float_as_int(v), sl));
}
__device__ __forceinline__ unsigned short f2bf(float f) {   // RNE
    unsigned u = __float_as_uint(f);
    return (unsigned short)((u + 0x7fffu + ((u >> 16) & 1u)) >> 16);
}
__device__ __forceinline__ float bflo(unsigned u) { return __uint_as_float(u << 16); }
__device__ __forceinline__ float bfhi(unsigned u) { return __uint_as_float(u & 0xffff0000u); }

// de Boor coefs (exact ref order) for one (b,i)
__device__ __forceinline__ void coef_eval(float xv, const float* t_sh,
                                          float& c0, float& c1, float& c2,
                                          float& c3, float& c4, int& g0) {
    int ik = 3 + (int)floorf((xv + 1.0f) * 32.0f);
    ik = min(max(ik, 3), 66);
    while (ik < 66 && xv >= t_sh[ik + 1]) ++ik;
    while (ik > 3 && xv < t_sh[ik]) --ik;
    float l0, l1, l2, r0, r1, r2;
    float N0 = 1.0f, N1, N2, N3;
    l0 = xv - t_sh[ik];  r0 = t_sh[ik + 1] - xv;
    { float temp = N0 / (r0 + l0); N0 = r0 * temp; N1 = l0 * temp; }
    l1 = xv - t_sh[ik - 1];  r1 = t_sh[ik + 2] - xv;
    { float saved = 0.0f, temp;
      temp = N0 / (r0 + l1); N0 = saved + r0 * temp; saved = l1 * temp;
      temp = N1 / (r1 + l0); N1 = saved + r1 * temp; N2 = l0 * temp; }
    l2 = xv - t_sh[ik - 2];  r2 = t_sh[ik + 3] - xv;
    { float saved = 0.0f, temp;
      temp = N0 / (r0 + l2); N0 = saved + r0 * temp; saved = l2 * temp;
      temp = N1 / (r1 + l1); N1 = saved + r1 * temp; saved = l1 * temp;
      temp = N2 / (r2 + l0); N2 = saved + r2 * temp; N3 = l0 * temp; }
    c0 = N0; c1 = N1; c2 = N2; c3 = N3;
    c4 = xv / (1.0f + expf(-xv));
    g0 = ik - 3;
}

// w f32 [GK][I][O] -> bf16 [I][GK][O] (transpose g<->i, o innermost).
// 1088 blocks x 256 thr; 8 (g,i) pairs/block x 32 o-quads. All coalesced.
__global__ __launch_bounds__(256)
void wcvt(const float* __restrict__ w, unsigned short* __restrict__ wbf) {
    const int tid = threadIdx.x;
    const int p   = blockIdx.x * 8 + (tid >> 5);    // (g,i) in source order
    const int oq  = (tid & 31) * 4;
    const int g   = p >> 7;
    const int i   = p & 127;
    const float4 v = *(const float4*)(w + (size_t)p * O_DIM + oq);
    ushort4 o4;
    o4.x = f2bf(v.x); o4.y = f2bf(v.y); o4.z = f2bf(v.z); o4.w = f2bf(v.w);
    *(ushort4*)(wbf + ((size_t)i * GK + g) * O_DIM + oq) = o4;
}

// grid = 256 blocks (1/CU), 512 thr = 8 waves; wave's b = blockIdx*8 + wave.
// ALL waves traverse i = 0..127 in the same order -> per-i block working set
// ~27 rows (~7 KB) is L1-resident; silu row 8x-reused from L1.
// Lane covers o = {2l, 2l+1}. Coefs: lane precomputes i=lane (set A) and
// i=lane+64 (set B); broadcast via readlane. Direct store, no reduction.
__global__ __launch_bounds__(512, 2)
void flashkan_sync(const float* __restrict__ x,
                   const unsigned short* __restrict__ wbf,
                   const float* __restrict__ t,
                   float* __restrict__ out) {
    __shared__ float t_sh[NKNOT];

    const int tid  = threadIdx.x;
    const int wave = tid >> 6;
    const int lane = tid & 63;
    const int b    = blockIdx.x * 8 + wave;

    if (tid < NKNOT) t_sh[tid] = t[tid];
    __syncthreads();

    // ---- coef phase: lane owns i = lane (A) and i = lane + 64 (B) ----
    float a0, a1, a2, a3, a4;  int ga;
    float b0, b1, b2, b3, b4;  int gb;
    coef_eval(x[(size_t)b * I_DIM + lane],      t_sh, a0, a1, a2, a3, a4, ga);
    coef_eval(x[(size_t)b * I_DIM + lane + 64], t_sh, b0, b1, b2, b3, b4, gb);

    const unsigned* wdw = (const unsigned*)wbf;
    float ax = 0.0f, ay = 0.0f;

    #pragma unroll 4
    for (int k = 0; k < 64; ++k) {
        const float c0 = rdlanef(a0, k), c1 = rdlanef(a1, k);
        const float c2 = rdlanef(a2, k), c3 = rdlanef(a3, k);
        const float c4 = rdlanef(a4, k);
        const int   g0 = __builtin_amdgcn_readlane(ga, k);

        const unsigned* rp = wdw + (size_t)k * SLICE_DW + g0 * ROW_DW + lane;
        const unsigned* sp = wdw + (size_t)k * SLICE_DW + 67 * ROW_DW + lane;
        const unsigned u0 = rp[0];
        const unsigned u1 = rp[ROW_DW];
        const unsigned u2 = rp[2 * ROW_DW];
        const unsigned u3 = rp[3 * ROW_DW];
        const unsigned u4 = *sp;

        ax += c0 * bflo(u0) + c1 * bflo(u1) + c2 * bflo(u2)
            + c3 * bflo(u3) + c4 * bflo(u4);
        ay += c0 * bfhi(u0) + c1 * bfhi(u1) + c2 * bfhi(u2)
            + c3 * bfhi(u3) + c4 * bfhi(u4);
    }

    #pragma unroll 4
    for (int k = 0; k < 64; ++k) {
        const float c0 = rdlanef(b0, k), c1 = rdlanef(b1, k);
        const float c2 = rdlanef(b2, k), c3 = rdlanef(b3, k);
        const float c4 = rdlanef(b4, k);
        const int   g0 = __builtin_amdgcn_readlane(gb, k);

        const unsigned* rp = wdw + (size_t)(k + 64) * SLICE_DW + g0 * ROW_DW + lane;
        const unsigned* sp = wdw + (size_t)(k + 64) * SLICE_DW + 67 * ROW_DW + lane;
        const unsigned u0 = rp[0];
        const unsigned u1 = rp[ROW_DW];
        const unsigned u2 = rp[2 * ROW_DW];
        const unsigned u3 = rp[3 * ROW_DW];
        const unsigned u4 = *sp;

        ax += c0 * bflo(u0) + c1 * bflo(u1) + c2 * bflo(u2)
            + c3 * bflo(u3) + c4 * bflo(u4);
        ay += c0 * bfhi(u0) + c1 * bfhi(u1) + c2 * bfhi(u2)
            + c3 * bfhi(u3) + c4 * bfhi(u4);
    }

    // ---- direct store: lane owns o = {2l, 2l+1} of its wave's b ----
    *(float2*)(out + (size_t)b * O_DIM + lane * 2) = make_float2(ax, ay);
}

// Fallback: R9 direct f32 gather (no ws needed).
__global__ __launch_bounds__(256)
void flashkan_gather_f32(const float* __restrict__ x,
                         const float* __restrict__ w,
                         const float* __restrict__ t,
                         float* __restrict__ out) {
    __shared__ float t_sh[NKNOT];
    __shared__ float psum[4][O_DIM];
    const int tid  = threadIdx.x;
    const int b    = blockIdx.x;
    const int wave = tid >> 6;
    const int lane = tid & 63;
    const int l32  = lane & 31;
    if (tid < NKNOT) t_sh[tid] = t[tid];
    __syncthreads();
    float cf0, cf1, cf2, cf3, cf4; int cg;
    coef_eval(x[(size_t)b * I_DIM + wave * 32 + l32], t_sh,
              cf0, cf1, cf2, cf3, cf4, cg);
    const int i_base = wave * 32;
    float ax = 0.0f, ay = 0.0f;
    #pragma unroll 8
    for (int k = 0; k < 32; ++k) {
        const float c0 = rdlanef(cf0, k), c1 = rdlanef(cf1, k);
        const float c2 = rdlanef(cf2, k), c3 = rdlanef(cf3, k);
        const float c4 = rdlanef(cf4, k);
        const int   g0 = __builtin_amdgcn_readlane(cg, k);
        const int i = i_base + k;
        const float2* base = (const float2*)(w + (size_t)i * O_DIM) + lane;
        const size_t rs = (size_t)I_DIM * O_DIM / 2;
        const float2 v0 = base[(size_t)g0 * rs];
        const float2 v1 = base[(size_t)(g0 + 1) * rs];
        const float2 v2 = base[(size_t)(g0 + 2) * rs];
        const float2 v3 = base[(size_t)(g0 + 3) * rs];
        const float2 v4 = base[(size_t)(GK - 1) * rs];
        ax += c0 * v0.x + c1 * v1.x + c2 * v2.x + c3 * v3.x + c4 * v4.x;
        ay += c0 * v0.y + c1 * v1.y + c2 * v2.y + c3 * v3.y + c4 * v4.y;
    }
    psum[wave][lane * 2]     = ax;
    psum[wave][lane * 2 + 1] = ay;
    __syncthreads();
    if (tid < O_DIM) {
        out[(size_t)b * O_DIM + tid] =
            psum[0][tid] + psum[1][tid] + psum[2][tid] + psum[3][tid];
    }
}

extern "C" void kernel_launch(void* const* d_in, const int* in_sizes, int n_in,
                              void* d_out, int out_size, void* d_ws, size_t ws_size,
                              hipStream_t stream) {
    const float* x = (const float*)d_in[0];
    const float* w = (const float*)d_in[1];
    const float* t = (const float*)d_in[2];
    float* out = (float*)d_out;

    if (ws_size >= WS_MIN) {
        unsigned short* wbf = (unsigned short*)d_ws;
        wcvt<<<(int)(W_ELEMS / (8 * 128)), 256, 0, stream>>>(w, wbf);  // 1088
        flashkan_sync<<<B_TOTAL / 8, 512, 0, stream>>>(x, wbf, t, out);
    } else {
        flashkan_gather_f32<<<B_TOTAL, 256, 0, stream>>>(x, w, t, out);
    }
}